// Round 5
// baseline (104.300 us; speedup 1.0000x reference)
//
#include <hip/hip_runtime.h>

// B=32, C=16, RES=128, NA=64
// out[b,0,a,i] = bias + sum_j bilinear(y[b],...), y[b] = sum_c w[c]*x[b,c]
//
// LDS: guarded image (2-px zero border) as DUPLICATED fp16 column pairs:
// P[r][c] = (G[r][c], G[r][c+1]) half2 (4 B) -> all 4 taps = ONE ds_read2_b32.
// Row stride 139: for every one of the 64 angles, the per-lane address delta
// (139*sin+cos) mod 32 stays >= ~1.4 banks -> <=3-way bank aliasing (stride
// 133 hit an exact 96 = 0 mod 32 at angle k=8 -> ~20-way conflicts).
// Angles interleaved across blocks ({g, g+16, g+32, g+48}) to balance load.

#define B_   32
#define C_   16
#define RES  128
#define NA   64
#define SLDS 139            // row stride in half2 units (= dwords)
#define ROWS 132
#define LDSZ (ROWS * SLDS)  // 18348 dwords = 73392 B -> 2 blocks/CU

typedef _Float16 half2v __attribute__((ext_vector_type(2)));

// ---------------- Kernel 1: channel reduce (HBM-bound, ~roofline) ----------------
__global__ __launch_bounds__(256) void chan_reduce(const float* __restrict__ x,
                                                   const float* __restrict__ w,
                                                   float* __restrict__ y) {
    int t  = blockIdx.x * 256 + threadIdx.x;
    int b  = t >> 12;
    int r4 = t & 4095;
    const float4* xb = (const float4*)(x + (size_t)b * C_ * RES * RES);
    float wr[C_];
#pragma unroll
    for (int c = 0; c < C_; ++c) wr[c] = w[c];
    float4 acc = make_float4(0.f, 0.f, 0.f, 0.f);
#pragma unroll
    for (int c = 0; c < C_; ++c) {
        float4 v = xb[c * (RES * RES / 4) + r4];
        acc.x = fmaf(wr[c], v.x, acc.x);
        acc.y = fmaf(wr[c], v.y, acc.y);
        acc.z = fmaf(wr[c], v.z, acc.z);
        acc.w = fmaf(wr[c], v.w, acc.w);
    }
    ((float4*)y)[(size_t)b * (RES * RES / 4) + r4] = acc;
}

// ---------------- Kernel 2: radon from LDS fp16 pair-packed image ----------------
// grid = 32 batches x 16 groups, block = 512 threads
// thread t: angle = (t>>7)*16 + grp (wave-uniform, interleaved), i = t&127
__global__ __launch_bounds__(512) void radon_k(const float* __restrict__ y,
                                               const float* __restrict__ angles,
                                               const float* __restrict__ bias,
                                               float* __restrict__ out) {
    __shared__ half2v lds[LDSZ];
    const int bid = blockIdx.x;
    const int b   = bid >> 4;
    const int grp = bid & 15;
    const int t   = threadIdx.x;

    // ---- zero whole tile (guard band included); LDSZ/2 = 9174 float2 ----
    {
        float2* l2 = (float2*)lds;
#pragma unroll
        for (int p = 0; p < 18; ++p) {
            int idx = p * 512 + t;
            if (idx < LDSZ / 2) l2[idx] = make_float2(0.f, 0.f);
        }
    }
    __syncthreads();

    // ---- stage image as duplicated fp16 pairs into interior ----
    // pixel m lives at guard col m+2; P[r][c] = (G[r][c], G[r][c+1])
    {
        const float* yb = y + (size_t)b * RES * RES;
#pragma unroll
        for (int p = 0; p < 8; ++p) {
            int q = p * 512 + t;            // 4096 float4 tiles
            int r = q >> 5;                 // image row
            int k = q & 31;                 // float4 index in row
            float4 v = *(const float4*)(yb + r * RES + (k << 2));
            float v4 = (k < 31) ? yb[r * RES + (k << 2) + 4] : 0.f;
            half2v* row = &lds[(r + 2) * SLDS];
            int c0 = (k << 2) + 2;
            row[c0]     = half2v{(_Float16)v.x, (_Float16)v.y};
            row[c0 + 1] = half2v{(_Float16)v.y, (_Float16)v.z};
            row[c0 + 2] = half2v{(_Float16)v.z, (_Float16)v.w};
            row[c0 + 3] = half2v{(_Float16)v.w, (_Float16)v4};
            if (k == 0) row[1] = half2v{(_Float16)0.f, (_Float16)v.x};
        }
    }
    __syncthreads();

    const int a = (t >> 7) * 16 + grp;      // wave-uniform, interleaved angles
    const int i = t & 127;
    float th = angles[a];
    float s, c;
    __sincosf(th, &s, &c);

    const float ci = (float)i - 63.5f;
    const float Xi = fmaf(ci, c, 65.5f);    // +63.5 center, +2 guard offset
    const float Yi = fmaf(ci, s, 65.5f);

    float acc0 = 0.0f, acc1 = 0.0f;
#pragma unroll 16
    for (int j = 0; j < RES; ++j) {
        float cj = (float)j - 63.5f;
        float X  = fmaf(cj, -s, Xi);
        float Y  = fmaf(cj,  c, Yi);
        float fx = floorf(X), fy = floorf(Y);
        float wx = X - fx,    wy = Y - fy;
        float gx = fminf(fmaxf(fx, 0.0f), 130.0f);   // v_med3_f32
        float gy = fminf(fmaxf(fy, 0.0f), 130.0f);
        int addr = (int)fmaf(gy, (float)SLDS, gx);   // exact (< 2^24)
        half2v p0 = lds[addr];                       // (v00, v01)
        half2v p1 = lds[addr + SLDS];                // (v10, v11) — one ds_read2_b32
        float u  = 1.0f - wx;
        float A0 = 1.0f - wy;
        half2v wa = __builtin_bit_cast(half2v, __builtin_amdgcn_cvt_pkrtz(A0 * u, A0 * wx));
        half2v wb = __builtin_bit_cast(half2v, __builtin_amdgcn_cvt_pkrtz(wy * u, wy * wx));
        acc0 = __builtin_amdgcn_fdot2(p0, wa, acc0, false);
        acc1 = __builtin_amdgcn_fdot2(p1, wb, acc1, false);
    }

    out[b * (NA * RES) + a * RES + i] = (acc0 + acc1) + bias[0];
}

extern "C" void kernel_launch(void* const* d_in, const int* in_sizes, int n_in,
                              void* d_out, int out_size, void* d_ws, size_t ws_size,
                              hipStream_t stream) {
    const float* x      = (const float*)d_in[0];   // 32*16*128*128
    const float* angles = (const float*)d_in[1];   // 64
    const float* w      = (const float*)d_in[2];   // 16
    const float* bias   = (const float*)d_in[3];   // 1
    float* out = (float*)d_out;                    // 32*64*128 fp32
    float* y   = (float*)d_ws;                     // 2 MiB scratch

    chan_reduce<<<dim3(512), dim3(256), 0, stream>>>(x, w, y);
    radon_k<<<dim3(B_ * 16), dim3(512), 0, stream>>>(y, angles, bias, out);
}

// Round 6
// 98.046 us; speedup vs baseline: 1.0638x; 1.0638x over previous
//
#include <hip/hip_runtime.h>

// B=32, C=16, RES=128, NA=64
// out[b,0,a,i] = bias + sum_j bilinear(y[b],...), y[b] = sum_c w[c]*x[b,c]
//
// 2-BATCH AMORTIZATION: LDS element E[r][c] = (b0[r,c], b0[r,c+1],
// b1[r,c], b1[r,c+1]) as 4 x fp16 (8 B). One ds_read2_b64 (offsets 0,133)
// fetches all 8 taps for TWO batch-samples; addr/floor/med3/weight math is
// computed once and shared. 2-px zero guard band baked into the packed
// buffer by pack_pairs -> radon staging is a branch-free bulk copy.
// LDS 147456 B -> 1 block/CU (2 waves/SIMD); grid 256 blocks = 1/CU.

#define B_    32
#define C_    16
#define RES   128
#define NA    64
#define SLDS  133              // row stride in 8-B elements (ds_read2_b64 offset1=133 <= 255)
#define ROWS  132
#define NELEM (ROWS * SLDS)    // 17556 elements
#define NPAD  18432            // padded: 18432*8 B = 147456 = 512 thr * 18 uint4
#define NPAIR 16

typedef _Float16 half2v __attribute__((ext_vector_type(2)));

// ---------------- Kernel 1: channel reduce (HBM-bound, ~roofline) ----------------
__global__ __launch_bounds__(256) void chan_reduce(const float* __restrict__ x,
                                                   const float* __restrict__ w,
                                                   float* __restrict__ y) {
    int t  = blockIdx.x * 256 + threadIdx.x;
    int b  = t >> 12;
    int r4 = t & 4095;
    const float4* xb = (const float4*)(x + (size_t)b * C_ * RES * RES);
    float wr[C_];
#pragma unroll
    for (int c = 0; c < C_; ++c) wr[c] = w[c];
    float4 acc = make_float4(0.f, 0.f, 0.f, 0.f);
#pragma unroll
    for (int c = 0; c < C_; ++c) {
        float4 v = xb[c * (RES * RES / 4) + r4];
        acc.x = fmaf(wr[c], v.x, acc.x);
        acc.y = fmaf(wr[c], v.y, acc.y);
        acc.z = fmaf(wr[c], v.z, acc.z);
        acc.w = fmaf(wr[c], v.w, acc.w);
    }
    ((float4*)y)[(size_t)b * (RES * RES / 4) + r4] = acc;
}

// ---------------- Kernel 2: build guarded packed pair-images ----------------
// element (p, r, c): (b0[r-2,c-2], b0[r-2,c-1], b1[r-2,c-2], b1[r-2,c-1]),
// zeros for guard rows/cols/pad.  b0 = 2p, b1 = 2p+1.
__global__ __launch_bounds__(256) void pack_pairs(const float* __restrict__ y,
                                                  uint2* __restrict__ pk) {
    int flat = blockIdx.x * 256 + threadIdx.x;   // 16*18432 = 294912 total
    int p    = flat / NPAD;
    int rem  = flat - p * NPAD;
    uint2 val = make_uint2(0u, 0u);
    if (rem < NELEM) {
        int r = rem / SLDS;
        int c = rem - r * SLDS;
        if (r >= 2 && r <= 129 && c >= 1 && c <= 129) {
            int q = r - 2;          // image row
            int m = c - 2;          // first tap col, in [-1, 127]
            const float* y0 = y + (size_t)(2 * p) * (RES * RES) + q * RES;
            const float* y1 = y0 + RES * RES;
            float a0 = (m >= 0)  ? y0[m]     : 0.f;
            float a1 = (m < 127) ? y0[m + 1] : 0.f;
            float b0 = (m >= 0)  ? y1[m]     : 0.f;
            float b1 = (m < 127) ? y1[m + 1] : 0.f;
            val.x = __builtin_bit_cast(unsigned int, __builtin_amdgcn_cvt_pkrtz(a0, a1));
            val.y = __builtin_bit_cast(unsigned int, __builtin_amdgcn_cvt_pkrtz(b0, b1));
        }
    }
    pk[flat] = val;
}

// ---------------- Kernel 3: radon, 2 batches per block ----------------
// grid = 16 pairs x 16 groups = 256 blocks, 512 threads
// thread t: angle slot = t>>7 -> a = slot*16+grp (wave-uniform), i = t&127
__global__ __launch_bounds__(512) void radon_k(const uint2* __restrict__ pk,
                                               const float* __restrict__ angles,
                                               const float* __restrict__ bias,
                                               float* __restrict__ out) {
    __shared__ uint2 lds[NPAD];   // 147456 B
    const int bid = blockIdx.x;
    const int p   = bid >> 4;
    const int grp = bid & 15;
    const int t   = threadIdx.x;

    // ---- branch-free bulk stage: 18 uint4 per thread, guards included ----
    {
        const uint4* src = (const uint4*)(pk + (size_t)p * NPAD);
        uint4*       dst = (uint4*)lds;
#pragma unroll
        for (int k = 0; k < 18; ++k) dst[k * 512 + t] = src[k * 512 + t];
    }
    __syncthreads();

    const int a = (t >> 7) * 16 + grp;     // wave-uniform angle
    const int i = t & 127;
    float th = angles[a];
    float s, c;
    __sincosf(th, &s, &c);

    const float ci = (float)i - 63.5f;
    // X(j) = ci*c - (j-63.5)*s + 65.5 = Xb + j*(-s);  Y(j) = Yb + j*c
    const float Xb = fmaf(ci, c, fmaf(63.5f, s, 65.5f));
    const float Yb = fmaf(ci, s, fmaf(-63.5f, c, 65.5f));
    const float ns = -s;

    float acc00 = 0.f, acc01 = 0.f, acc10 = 0.f, acc11 = 0.f;
#pragma unroll 8
    for (int j = 0; j < RES; ++j) {
        float jf = (float)j;               // literal per unrolled instance
        float X  = fmaf(jf, ns, Xb);
        float Y  = fmaf(jf, c,  Yb);
        float fx = floorf(X), fy = floorf(Y);
        float wx = X - fx,    wy = Y - fy;
        float gx = fminf(fmaxf(fx, 0.f), 130.f);    // v_med3_f32
        float gy = fminf(fmaxf(fy, 0.f), 130.f);
        int addr = (int)fmaf(gy, (float)SLDS, gx);  // exact (< 2^24)
        uint2 q0 = lds[addr];                       // row gy:   (b0 pair, b1 pair)
        uint2 q1 = lds[addr + SLDS];                // row gy+1  — ds_read2_b64
        float u  = 1.f - wx;
        float A0 = 1.f - wy;
        half2v wa = __builtin_bit_cast(half2v, __builtin_amdgcn_cvt_pkrtz(A0 * u, A0 * wx));
        half2v wb = __builtin_bit_cast(half2v, __builtin_amdgcn_cvt_pkrtz(wy * u, wy * wx));
        acc00 = __builtin_amdgcn_fdot2(__builtin_bit_cast(half2v, q0.x), wa, acc00, false);
        acc10 = __builtin_amdgcn_fdot2(__builtin_bit_cast(half2v, q0.y), wa, acc10, false);
        acc01 = __builtin_amdgcn_fdot2(__builtin_bit_cast(half2v, q1.x), wb, acc01, false);
        acc11 = __builtin_amdgcn_fdot2(__builtin_bit_cast(half2v, q1.y), wb, acc11, false);
    }

    float bv = bias[0];
    out[(2 * p)     * (NA * RES) + a * RES + i] = (acc00 + acc01) + bv;
    out[(2 * p + 1) * (NA * RES) + a * RES + i] = (acc10 + acc11) + bv;
}

extern "C" void kernel_launch(void* const* d_in, const int* in_sizes, int n_in,
                              void* d_out, int out_size, void* d_ws, size_t ws_size,
                              hipStream_t stream) {
    const float* x      = (const float*)d_in[0];   // 32*16*128*128
    const float* angles = (const float*)d_in[1];   // 64
    const float* w      = (const float*)d_in[2];   // 16
    const float* bias   = (const float*)d_in[3];   // 1
    float* out = (float*)d_out;                    // 32*64*128 fp32

    float* y  = (float*)d_ws;                                  // 2 MiB fp32
    uint2* pk = (uint2*)((char*)d_ws + (size_t)4 * 1024 * 1024); // 2.36 MiB packed

    chan_reduce<<<dim3(512), dim3(256), 0, stream>>>(x, w, y);
    pack_pairs<<<dim3(NPAIR * NPAD / 256), dim3(256), 0, stream>>>(y, pk);
    radon_k<<<dim3(NPAIR * 16), dim3(512), 0, stream>>>(pk, angles, bias, out);
}